// Round 19
// baseline (343.305 us; speedup 1.0000x reference)
//
#include <hip/hip_runtime.h>

typedef unsigned short u16;
typedef unsigned char u8;
typedef __attribute__((ext_vector_type(8))) short bf16x8;
typedef __attribute__((ext_vector_type(4))) float f32x4;
typedef __attribute__((ext_vector_type(8))) u16 u16x8;
typedef __attribute__((ext_vector_type(2))) int i32x2;
typedef __attribute__((ext_vector_type(4))) int i32x4;
typedef __attribute__((ext_vector_type(2))) float f32x2;

#define GLOAD_LDS(g, s) __builtin_amdgcn_global_load_lds( \
    (const __attribute__((address_space(1))) void*)(g),   \
    (__attribute__((address_space(3))) void*)(s), 16, 0, 0)

__device__ __forceinline__ u16 f2bf(float f) {
  union { float f; unsigned u; } v; v.f = f;
  unsigned r = v.u + 0x7fffu + ((v.u >> 16) & 1u);
  return (u16)(r >> 16);
}
__device__ __forceinline__ float bf2f(u16 h) {
  union { unsigned u; float f; } v; v.u = ((unsigned)h) << 16;
  return v.f;
}

__device__ __forceinline__ unsigned lds_addr(const void* p) {
  return (unsigned)(unsigned long long)(__attribute__((address_space(3))) const void*)p;
}
__device__ __forceinline__ bf16x8 ds128(const void* p) {
  bf16x8 r;
  asm volatile("ds_read_b128 %0, %1" : "=v"(r) : "v"(lds_addr(p)));
  return r;
}
__device__ __forceinline__ i32x4 ds128i(const void* p) {
  i32x4 r;
  asm volatile("ds_read_b128 %0, %1" : "=v"(r) : "v"(lds_addr(p)));
  return r;
}
// 8 fp8(e4m3) -> 8 bf16 (elem order preserved)
__device__ __forceinline__ bf16x8 cvt8(i32x2 v) {
  f32x2 f0 = __builtin_amdgcn_cvt_pk_f32_fp8(v[0], false);
  f32x2 f1 = __builtin_amdgcn_cvt_pk_f32_fp8(v[0], true);
  f32x2 f2 = __builtin_amdgcn_cvt_pk_f32_fp8(v[1], false);
  f32x2 f3 = __builtin_amdgcn_cvt_pk_f32_fp8(v[1], true);
  unsigned w0, w1, w2, w3;
  asm("v_cvt_pk_bf16_f32 %0, %1, %2" : "=v"(w0) : "v"(f0[0]), "v"(f0[1]));
  asm("v_cvt_pk_bf16_f32 %0, %1, %2" : "=v"(w1) : "v"(f1[0]), "v"(f1[1]));
  asm("v_cvt_pk_bf16_f32 %0, %1, %2" : "=v"(w2) : "v"(f2[0]), "v"(f2[1]));
  asm("v_cvt_pk_bf16_f32 %0, %1, %2" : "=v"(w3) : "v"(f3[0]), "v"(f3[1]));
  union { unsigned w[4]; bf16x8 v8; } u;
  u.w[0] = w0; u.w[1] = w1; u.w[2] = w2; u.w[3] = w3;
  return u.v8;
}

// ====== 256x256 8-wave BK=64 core, A-deep(3buf)/B-shallow(2buf) ======
// Used by k_s and k_proj2 — proven ~1.2 TF with L2-resident operands.
__device__ __forceinline__ void stage_one(const u16* g, int ld, u16* d, int tid) {
  int rw = tid >> 3;
  int gs = ((tid & 7) ^ (rw & 7)) << 3;
  int wb = (tid >> 6) << 9;
#pragma unroll
  for (int p = 0; p < 4; p++)
    GLOAD_LDS(g + (long)(p * 64 + rw) * ld + gs, d + p * 4096 + wb);
}

__device__ __forceinline__ void gemm256d(f32x4 (&acc)[8][4],
    const u16* Ag, int lda, const u16* Bg, int ldb, int nk,
    u16* As, u16* Bs, int tid) {
  const int lane = tid & 63, wid = tid >> 6;
  const int wr = (wid >> 2) << 7;
  const int wc = (wid & 3) << 6;
  const int rl = lane & 15, kg = lane >> 4;
  const int swz0 = (kg ^ (rl & 7)) << 3;
  const int rbA = (wr + rl) * 64, rbB = (wc + rl) * 64;

  stage_one(Ag, lda, As, tid);
  stage_one(Bg, ldb, Bs, tid);
  if (nk > 1) stage_one(Ag + 64, lda, As + 16384, tid);

  int ba = 0;
  for (int t = 0; t < nk; ++t) {
    if (t + 1 < nk) asm volatile("s_waitcnt vmcnt(4)" ::: "memory");
    else            asm volatile("s_waitcnt vmcnt(0)" ::: "memory");
    __builtin_amdgcn_s_barrier();
    if (t + 1 < nk)
      stage_one(Bg + (t + 1) * 64, ldb, Bs + ((t + 1) & 1) * 16384, tid);
    if (t + 2 < nk) {
      int nb = ba + 2; if (nb >= 3) nb -= 3;
      stage_one(Ag + (long)(t + 2) * 64, lda, As + nb * 16384, tid);
    }
    const u16* ab = As + ba * 16384 + rbA;
    const u16* bb = Bs + (t & 1) * 16384 + rbB;
#pragma unroll
    for (int kk = 0; kk < 2; kk++) {
      const int sw = swz0 ^ (kk << 5);
      bf16x8 a[8], b[4];
#pragma unroll
      for (int i = 0; i < 8; i++) a[i] = ds128(ab + i * 1024 + sw);
#pragma unroll
      for (int j = 0; j < 4; j++) b[j] = ds128(bb + j * 1024 + sw);
      asm volatile("s_waitcnt lgkmcnt(0)" ::: "memory");
      __builtin_amdgcn_sched_barrier(0);
      __builtin_amdgcn_s_setprio(1);
#pragma unroll
      for (int i = 0; i < 8; i++)
#pragma unroll
        for (int j = 0; j < 4; j++)
          acc[i][j] = __builtin_amdgcn_mfma_f32_16x16x32_bf16(a[i], b[j], acc[i][j], 0, 0, 0);
      __builtin_amdgcn_s_setprio(0);
      __builtin_amdgcn_sched_barrier(0);
    }
    ba = ba + 1; if (ba == 3) ba = 0;
  }
}

// ====== PV core: 256x128, BK=64, A fp8 LDS 3buf / B bf16 LDS 2buf = 80KB ======
// 2 blocks/CU; never-drain (steady vmcnt(2)). NEW (r19): per-phase interleave
// (T3): each K-tile = 4 phases of {ds_reads -> ONE global_load_lds unit ->
// barrier -> lgkmcnt(0) -> setprio(1) 8xMFMA setprio(0) -> barrier}. Stage
// units: B(t+1) in P0/P1, A(t+2) in P2/P3 -> continuous load-issue stream.
// Layouts/swizzles identical to r18 (0 bank conflicts, verified).
__device__ __forceinline__ void stage_A64(const u8* gA, u8* Ad, int tid) {
#pragma unroll
  for (int pass = 0; pass < 2; pass++) {
    int gid = pass * 512 + tid;
    int row = gid >> 2, g = gid & 3;
    GLOAD_LDS(gA + (long)row * 2048 + ((g ^ ((row >> 1) & 3)) << 4), Ad + (gid << 4));
  }
}
__device__ __forceinline__ void stage_B64(const u16* gB, u8* Bd, int tid) {
#pragma unroll
  for (int pass = 0; pass < 2; pass++) {
    int gid = pass * 512 + tid;
    int row = gid >> 3, g = gid & 7;
    GLOAD_LDS(gB + (long)row * 2048 + ((g ^ (row & 7)) << 3), Bd + (gid << 4));
  }
}
__device__ __forceinline__ void stage_A64u(const u8* gA, u8* Ad, int tid, int pass) {
  int gid = pass * 512 + tid;
  int row = gid >> 2, g = gid & 3;
  GLOAD_LDS(gA + (long)row * 2048 + ((g ^ ((row >> 1) & 3)) << 4), Ad + (gid << 4));
}
__device__ __forceinline__ void stage_B64u(const u16* gB, u8* Bd, int tid, int pass) {
  int gid = pass * 512 + tid;
  int row = gid >> 3, g = gid & 7;
  GLOAD_LDS(gB + (long)row * 2048 + ((g ^ (row & 7)) << 3), Bd + (gid << 4));
}

__device__ __forceinline__ void gemm_pv8(f32x4 (&acc)[4][4],
    const u8* Ag, const u16* Bg, u8* As, u8* Bs, int tid) {
  const int lane = tid & 63, wid = tid >> 6;
  const int mq = wid >> 1, nh = wid & 1;        // 4M x 2N waves, 64x64 each
  const int rl = lane & 15, kg = lane >> 4;
  const int nk = 16;                             // K = 1024 (kc-split half)
  const int abase = (mq * 64 + rl) * 64;
  const int aswz = (kg ^ ((rl >> 1) & 3)) << 4;
  const int bbase = (nh * 64 + rl) * 128;
  const int bs0 = (kg ^ (rl & 7)) << 4;
  const int bs1 = ((4 + kg) ^ (rl & 7)) << 4;

  stage_A64(Ag, As, tid);                        // A(0): 2 loads
  stage_B64(Bg, Bs, tid);                        // B(0): 2 loads
  stage_A64(Ag + 64, As + 16384, tid);           // A(1): 2 loads
  int ba = 0;
  for (int t = 0; t < nk; ++t) {
    // boundary: A(t),B(t) landed; A(t+1) (2 loads) stays in flight
    if (t + 1 < nk) asm volatile("s_waitcnt vmcnt(2)" ::: "memory");
    else            asm volatile("s_waitcnt vmcnt(0)" ::: "memory");
    __builtin_amdgcn_s_barrier();
    const u8* ab = As + ba * 16384 + abase;
    const u8* bb = Bs + (t & 1) * 16384 + bbase;
    const bool sB = (t + 1 < nk), sA = (t + 2 < nk);
    int nb = ba + 2; if (nb >= 3) nb -= 3;
    i32x4 a4[4]; bf16x8 b0[4], b1[4], alo[4], ahi[4];
    // ---------------- P0: a4 + b0[0..1]; stage B(t+1)u0; MFMA kk0 j0-1 ----------------
#pragma unroll
    for (int i = 0; i < 4; i++) a4[i] = ds128i(ab + i * 1024 + aswz);
    b0[0] = ds128(bb + bs0);
    b0[1] = ds128(bb + 2048 + bs0);
    if (sB) stage_B64u(Bg + (t + 1) * 64, Bs + ((t + 1) & 1) * 16384, tid, 0);
    __builtin_amdgcn_s_barrier();
    asm volatile("s_waitcnt lgkmcnt(0)" ::: "memory");
    __builtin_amdgcn_sched_barrier(0);
#pragma unroll
    for (int i = 0; i < 4; i++) { i32x2 lo; lo[0] = a4[i][0]; lo[1] = a4[i][1]; alo[i] = cvt8(lo); }
    __builtin_amdgcn_s_setprio(1);
#pragma unroll
    for (int i = 0; i < 4; i++)
#pragma unroll
      for (int j = 0; j < 2; j++)
        acc[i][j] = __builtin_amdgcn_mfma_f32_16x16x32_bf16(alo[i], b0[j], acc[i][j], 0, 0, 0);
    __builtin_amdgcn_s_setprio(0);
    __builtin_amdgcn_sched_barrier(0);
    __builtin_amdgcn_s_barrier();
    // ---------------- P1: b0[2..3]; stage B(t+1)u1; MFMA kk0 j2-3 ----------------
    b0[2] = ds128(bb + 2 * 2048 + bs0);
    b0[3] = ds128(bb + 3 * 2048 + bs0);
    if (sB) stage_B64u(Bg + (t + 1) * 64, Bs + ((t + 1) & 1) * 16384, tid, 1);
    __builtin_amdgcn_s_barrier();
    asm volatile("s_waitcnt lgkmcnt(0)" ::: "memory");
    __builtin_amdgcn_sched_barrier(0);
    __builtin_amdgcn_s_setprio(1);
#pragma unroll
    for (int i = 0; i < 4; i++)
#pragma unroll
      for (int j = 2; j < 4; j++)
        acc[i][j] = __builtin_amdgcn_mfma_f32_16x16x32_bf16(alo[i], b0[j], acc[i][j], 0, 0, 0);
    __builtin_amdgcn_s_setprio(0);
    __builtin_amdgcn_sched_barrier(0);
    __builtin_amdgcn_s_barrier();
    // ---------------- P2: b1[0..1]; stage A(t+2)u0; MFMA kk1 j0-1 ----------------
    b1[0] = ds128(bb + bs1);
    b1[1] = ds128(bb + 2048 + bs1);
    if (sA) stage_A64u(Ag + (long)(t + 2) * 64, As + nb * 16384, tid, 0);
    __builtin_amdgcn_s_barrier();
    asm volatile("s_waitcnt lgkmcnt(0)" ::: "memory");
    __builtin_amdgcn_sched_barrier(0);
#pragma unroll
    for (int i = 0; i < 4; i++) { i32x2 hi; hi[0] = a4[i][2]; hi[1] = a4[i][3]; ahi[i] = cvt8(hi); }
    __builtin_amdgcn_s_setprio(1);
#pragma unroll
    for (int i = 0; i < 4; i++)
#pragma unroll
      for (int j = 0; j < 2; j++)
        acc[i][j] = __builtin_amdgcn_mfma_f32_16x16x32_bf16(ahi[i], b1[j], acc[i][j], 0, 0, 0);
    __builtin_amdgcn_s_setprio(0);
    __builtin_amdgcn_sched_barrier(0);
    __builtin_amdgcn_s_barrier();
    // ---------------- P3: b1[2..3]; stage A(t+2)u1; MFMA kk1 j2-3 ----------------
    b1[2] = ds128(bb + 2 * 2048 + bs1);
    b1[3] = ds128(bb + 3 * 2048 + bs1);
    if (sA) stage_A64u(Ag + (long)(t + 2) * 64, As + nb * 16384, tid, 1);
    __builtin_amdgcn_s_barrier();
    asm volatile("s_waitcnt lgkmcnt(0)" ::: "memory");
    __builtin_amdgcn_sched_barrier(0);
    __builtin_amdgcn_s_setprio(1);
#pragma unroll
    for (int i = 0; i < 4; i++)
#pragma unroll
      for (int j = 2; j < 4; j++)
        acc[i][j] = __builtin_amdgcn_mfma_f32_16x16x32_bf16(ahi[i], b1[j], acc[i][j], 0, 0, 0);
    __builtin_amdgcn_s_setprio(0);
    __builtin_amdgcn_sched_barrier(0);
    // trailing barrier is the next tile's boundary barrier
    ba = ba + 1; if (ba == 3) ba = 0;
  }
}

// ---------------- conversion kernels ----------------
__global__ __launch_bounds__(256) void k_cvt2(const float* __restrict__ inX,
                                              const float* __restrict__ inY,
                                              u16* __restrict__ oX, u16* __restrict__ oY,
                                              int n8) {
  int i = blockIdx.x * 256 + threadIdx.x;
  const float* in = (i < n8) ? inX : inY;
  u16* out = (i < n8) ? oX : oY;
  int k = (i < n8) ? i : i - n8;
  const float4* pf = (const float4*)in + (long)k * 2;
  float4 a = pf[0], b = pf[1];
  u16x8 o;
  o[0] = f2bf(a.x); o[1] = f2bf(a.y); o[2] = f2bf(a.z); o[3] = f2bf(a.w);
  o[4] = f2bf(b.x); o[5] = f2bf(b.y); o[6] = f2bf(b.z); o[7] = f2bf(b.w);
  *((u16x8*)out + k) = o;
}

struct P6 { const float* p[6]; };
struct O6 { u16* p[6]; };

__global__ __launch_bounds__(256) void k_cvt_w(P6 w, u16* __restrict__ out) {
  int z = blockIdx.y;
  int i = blockIdx.x * 256 + threadIdx.x;
  const float4* pf = (const float4*)w.p[z] + (long)i * 2;
  float4 a = pf[0], b = pf[1];
  u16x8 o;
  o[0] = f2bf(a.x); o[1] = f2bf(a.y); o[2] = f2bf(a.z); o[3] = f2bf(a.w);
  o[4] = f2bf(b.x); o[5] = f2bf(b.y); o[6] = f2bf(b.z); o[7] = f2bf(b.w);
  *((u16x8*)(out + (long)z * 262144) + i) = o;
}

// ---------------- projections (gemm256d core) ----------------
__global__ __launch_bounds__(512) void k_proj2(const u16* __restrict__ Xb, const u16* __restrict__ Yb,
                                               const u16* __restrict__ Wb, P6 bias, O6 dst) {
  __shared__ u16 As[49152], Bs[32768];
  int x = blockIdx.x;
  int swz = (x & 7) * 96 + (x >> 3);
  int grp = swz >= 384;
  int r = grp ? swz - 384 : swz;
  int bm = r / 6, bn = r - bm * 6;
  int tid = threadIdx.x;
  const u16* Ag = (grp ? Yb : Xb) + (long)bm * 256 * 512;
  const u16* Bg = Wb + (long)grp * 786432 + (long)bn * 256 * 512;
  f32x4 acc[8][4] = {};
  gemm256d(acc, Ag, 512, Bg, 512, 8, As, Bs, tid);
  int z = grp * 3 + (bn >> 1);
  const float* bi = bias.p[z];
  u16* D = dst.p[z];
  int lane = tid & 63, wid = tid >> 6;
  int row0 = bm * 256 + ((wid >> 2) << 7) + ((lane >> 4) << 2);
  int colz = (bn & 1) * 256 + ((wid & 3) << 6) + (lane & 15);
  float bj[4];
#pragma unroll
  for (int j = 0; j < 4; j++) bj[j] = bi[colz + (j << 4)];
#pragma unroll
  for (int i = 0; i < 8; i++)
#pragma unroll
    for (int j = 0; j < 4; j++)
#pragma unroll
      for (int rr = 0; rr < 4; rr++)
        D[(long)(row0 + (i << 4) + rr) * 512 + colz + (j << 4)] = f2bf(acc[i][j][rr] + bj[j]);
}

// ---------------- scores (gemm256d): XCD chunk = one batch b ----------------
__global__ __launch_bounds__(512) void k_s(const u16* __restrict__ Q, const u16* __restrict__ K,
                                           u16* __restrict__ S) {
  __shared__ u16 As[49152], Bs[32768];
  int x = blockIdx.x;
  int swz = (x & 7) * 64 + (x >> 3);         // 512 blocks, chunk=64 = one b
  int bn = swz & 7, bm = (swz >> 3) & 7, b = swz >> 6;
  int tid = threadIdx.x;
  const u16* Ag = Q + (long)b * 1048576 + (long)bm * 256 * 512;
  const u16* Bg = K + (long)b * 1048576 + (long)bn * 256 * 512;
  f32x4 acc[8][4] = {};
  gemm256d(acc, Ag, 512, Bg, 512, 8, As, Bs, tid);
  u16* D = S + (long)b * 4194304;
  const float scale = 0.04419417382415922f;  // 1/sqrt(512)
  int lane = tid & 63, wid = tid >> 6;
  int row0 = bm * 256 + ((wid >> 2) << 7) + ((lane >> 4) << 2);
  int col0 = bn * 256 + ((wid & 3) << 6) + (lane & 15);
#pragma unroll
  for (int i = 0; i < 8; i++)
#pragma unroll
    for (int j = 0; j < 4; j++)
#pragma unroll
      for (int rr = 0; rr < 4; rr++)
        D[(long)(row0 + (i << 4) + rr) * 2048 + col0 + (j << 4)] = f2bf(acc[i][j][rr] * scale);
}

// ---------------- softmax over batch axis -> fp8 e4m3, kk-interleaved ----------------
// Within each 64B k-group of a row, chunk c (kk*4+kg order) is stored at
// c' = kg*2 + kk so PV can read [kg kk0|kg kk1] with one b128.
__global__ __launch_bounds__(256) void k_softmax8(const u16* __restrict__ S,
                                                  u8* __restrict__ A8) {
  int idx = blockIdx.x * 256 + threadIdx.x;   // 2048 blocks; 8 m-positions each
  u16x8 v[8];
#pragma unroll
  for (int b = 0; b < 8; b++) v[b] = *((const u16x8*)(S + (long)b * 4194304) + idx);
  unsigned w0[8], w1[8];
#pragma unroll
  for (int jp = 0; jp < 4; jp++) {
    float va[8], vb[8];
    {
      float e[8], m = -1e30f;
#pragma unroll
      for (int b = 0; b < 8; b++) { e[b] = bf2f(v[b][2 * jp]); m = fmaxf(m, e[b]); }
      float s = 0.f;
#pragma unroll
      for (int b = 0; b < 8; b++) { e[b] = __expf(e[b] - m); s += e[b]; }
      float inv = 1.0f / s;
#pragma unroll
      for (int b = 0; b < 8; b++) va[b] = e[b] * inv;
    }
    {
      float e[8], m = -1e30f;
#pragma unroll
      for (int b = 0; b < 8; b++) { e[b] = bf2f(v[b][2 * jp + 1]); m = fmaxf(m, e[b]); }
      float s = 0.f;
#pragma unroll
      for (int b = 0; b < 8; b++) { e[b] = __expf(e[b] - m); s += e[b]; }
      float inv = 1.0f / s;
#pragma unroll
      for (int b = 0; b < 8; b++) vb[b] = e[b] * inv;
    }
#pragma unroll
    for (int b = 0; b < 8; b++) {
      if (jp == 0)      w0[b] = __builtin_amdgcn_cvt_pk_fp8_f32(va[b], vb[b], 0,     false);
      else if (jp == 1) w0[b] = __builtin_amdgcn_cvt_pk_fp8_f32(va[b], vb[b], w0[b], true);
      else if (jp == 2) w1[b] = __builtin_amdgcn_cvt_pk_fp8_f32(va[b], vb[b], 0,     false);
      else              w1[b] = __builtin_amdgcn_cvt_pk_fp8_f32(va[b], vb[b], w1[b], true);
    }
  }
  // permuted chunk index: c' = (c & ~7) | ((c&3)<<1) | ((c>>2)&1)
  long cp = ((long)idx & ~7L) | (((long)idx & 3) << 1) | (((long)idx >> 2) & 1);
#pragma unroll
  for (int b = 0; b < 8; b++) {
    i32x2 w; w[0] = (int)w0[b]; w[1] = (int)w1[b];
    *(i32x2*)(A8 + (long)b * 4194304 + cp * 8) = w;
  }
}

// ---------------- V transpose (bf16, unchanged) ----------------
__global__ __launch_bounds__(256) void k_tr(const u16* __restrict__ V1, const u16* __restrict__ V2,
                                            u16* __restrict__ T1, u16* __restrict__ T2) {
  __shared__ u16 tile[64][65];
  int z = blockIdx.z;
  const u16* src = (z < 8 ? V1 : V2) + (long)(z & 7) * 1048576;
  u16*       dst = (z < 8 ? T1 : T2) + (long)(z & 7) * 1048576;
  int n0 = blockIdx.x * 64, d0 = blockIdx.y * 64;
  int t = threadIdx.x;
  int r = t >> 2, cs = (t & 3) * 16;
  const u16x8* sp = (const u16x8*)(src + (long)(n0 + r) * 512 + d0 + cs);
  u16x8 a = sp[0], b = sp[1];
#pragma unroll
  for (int jj = 0; jj < 8; jj++) { tile[r][cs + jj] = a[jj]; tile[r][cs + 8 + jj] = b[jj]; }
  __syncthreads();
  u16x8 o0, o1;
#pragma unroll
  for (int jj = 0; jj < 8; jj++) { o0[jj] = tile[cs + jj][r]; o1[jj] = tile[cs + 8 + jj][r]; }
  u16x8* op = (u16x8*)(dst + (long)(d0 + r) * 2048 + n0 + cs);
  op[0] = o0; op[1] = o1;
}

// ---------------- merged PV: out/P tiles from A2.V1 + A1.V2 ----------------
// 512 blocks (2/CU), kc-split: kc0 -> out = acc + X + Y ; kc1 -> P = acc.
__global__ __launch_bounds__(512) void k_pv8m(const u8* __restrict__ A2, const u16* __restrict__ Vt1,
                                              const u8* __restrict__ A1, const u16* __restrict__ Vt2,
                                              const float* __restrict__ X, const float* __restrict__ Y,
                                              float* __restrict__ out, float* __restrict__ P) {
  __shared__ u8 As[49152], Bs[32768];   // 80KB -> 2 blocks/CU
  int x = blockIdx.x;
  int swz = (x & 7) * 64 + (x >> 3);    // XCD chunk = one b (64 blocks)
  int b = swz >> 6;
  int r = swz & 63;
  int bn = r & 3, kc = (r >> 2) & 1, bm = r >> 3;
  int tid = threadIdx.x;
  long aoff = (long)b * 4194304 + (long)bm * 256 * 2048 + kc * 1024;
  long voff = (long)b * 1048576 + (long)bn * 128 * 2048 + kc * 1024;
  f32x4 acc[4][4] = {};
  gemm_pv8(acc, A2 + aoff, Vt1 + voff, As, Bs, tid);   // attention 2 half
  __builtin_amdgcn_s_barrier();                        // LDS reuse between halves
  gemm_pv8(acc, A1 + aoff, Vt2 + voff, As, Bs, tid);   // attention 1 half
  int lane = tid & 63, wid = tid >> 6;
  int mq = wid >> 1, nh = wid & 1;
  int row0 = bm * 256 + mq * 64 + ((lane >> 4) << 2);
  int col0 = bn * 128 + nh * 64 + (lane & 15);
  long base = (long)b * 1048576;
#pragma unroll
  for (int i = 0; i < 4; i++)
#pragma unroll
    for (int j = 0; j < 4; j++)
#pragma unroll
      for (int rr = 0; rr < 4; rr++) {
        long idx = base + (long)(row0 + (i << 4) + rr) * 512 + col0 + (j << 4);
        float v = acc[i][j][rr];
        if (kc) P[idx] = v;
        else    out[idx] = v + X[idx] + Y[idx];
      }
}

// ---------------- final: out += P ----------------
__global__ __launch_bounds__(256) void k_fin(float* __restrict__ out, const float* __restrict__ P) {
  long i = (long)(blockIdx.x * 256 + threadIdx.x) * 4;
  float4 o = *(const float4*)(out + i);
  float4 p = *(const float4*)(P + i);
  o.x += p.x; o.y += p.y; o.z += p.z; o.w += p.w;
  *(float4*)(out + i) = o;
}

extern "C" void kernel_launch(void* const* d_in, const int* in_sizes, int n_in,
                              void* d_out, int out_size, void* d_ws, size_t ws_size,
                              hipStream_t stream) {
  const float* X = (const float*)d_in[0];
  const float* Y = (const float*)d_in[1];
  P6 wp, bp;
  for (int i = 0; i < 6; i++) { wp.p[i] = (const float*)d_in[2 + 2 * i]; bp.p[i] = (const float*)d_in[3 + 2 * i]; }

  const long NX = 8L * 2048 * 512;
  const long NS = 8L * 2048 * 2048;
  u16* p = (u16*)d_ws;
  u16* Xb = p;  p += NX;                  // bf16 X (reused as Vt1)
  u16* Yb = p;  p += NX;                  // bf16 Y (reused as Vt2)
  u16* Wb = p;  p += 6L * 512 * 512;
  u16* Q1 = p;  p += NX;                  // Q1+K2 adjacent -> A8_1 after softmax
  u16* K2 = p;  p += NX;
  u16* Q2 = p;  p += NX;                  // Q2+K1 adjacent -> A8_2 after softmax
  u16* K1 = p;  p += NX;
  u16* Sb = p;  p += NS;                  // S buffer; dead after softmaxes -> Pbuf
  u16* V1 = Sb;
  u16* V2 = Sb + NX;
  u16* Vt1 = Xb;
  u16* Vt2 = Yb;
  u8* A8_2 = (u8*)Q2;                     // NS bytes over dead Q2+K1
  u8* A8_1 = (u8*)Q1;                     // NS bytes over dead Q1+K2
  float* Pbuf = (float*)Sb;               // NX f32 over dead Sb
  (void)ws_size; (void)in_sizes; (void)n_in; (void)out_size;

  dim3 T(256);
  k_cvt2<<<dim3(8192), T, 0, stream>>>(X, Y, Xb, Yb, (int)(NX / 8));
  k_cvt_w<<<dim3(128, 6), T, 0, stream>>>(wp, Wb);
  O6 dst; dst.p[0] = Q1; dst.p[1] = K1; dst.p[2] = V1; dst.p[3] = Q2; dst.p[4] = K2; dst.p[5] = V2;
  k_proj2<<<dim3(768), dim3(512), 0, stream>>>(Xb, Yb, Wb, bp, dst);
  k_tr<<<dim3(32, 8, 16), T, 0, stream>>>(V1, V2, Vt1, Vt2);
  // both score+softmax phases first (frees Sb before PV)
  k_s<<<dim3(512), dim3(512), 0, stream>>>(Q2, K1, Sb);
  k_softmax8<<<dim3(2048), T, 0, stream>>>(Sb, A8_2);
  k_s<<<dim3(512), dim3(512), 0, stream>>>(Q1, K2, Sb);
  k_softmax8<<<dim3(2048), T, 0, stream>>>(Sb, A8_1);
  // merged PV: out(kc0) = A2.V1 + A1.V2 + X + Y ; P(kc1) = partial
  k_pv8m<<<dim3(512), dim3(512), 0, stream>>>(A8_2, Vt1, A8_1, Vt2, X, Y, (float*)d_out, Pbuf);
  // out += P
  k_fin<<<dim3((int)(NX / 1024)), T, 0, stream>>>((float*)d_out, Pbuf);
}

// Round 20
// 302.977 us; speedup vs baseline: 1.1331x; 1.1331x over previous
//
#include <hip/hip_runtime.h>

typedef unsigned short u16;
typedef unsigned char u8;
typedef __attribute__((ext_vector_type(8))) short bf16x8;
typedef __attribute__((ext_vector_type(4))) float f32x4;
typedef __attribute__((ext_vector_type(8))) u16 u16x8;
typedef __attribute__((ext_vector_type(2))) int i32x2;
typedef __attribute__((ext_vector_type(4))) int i32x4;
typedef __attribute__((ext_vector_type(2))) float f32x2;

#define GLOAD_LDS(g, s) __builtin_amdgcn_global_load_lds( \
    (const __attribute__((address_space(1))) void*)(g),   \
    (__attribute__((address_space(3))) void*)(s), 16, 0, 0)

__device__ __forceinline__ u16 f2bf(float f) {
  union { float f; unsigned u; } v; v.f = f;
  unsigned r = v.u + 0x7fffu + ((v.u >> 16) & 1u);
  return (u16)(r >> 16);
}
__device__ __forceinline__ float bf2f(u16 h) {
  union { unsigned u; float f; } v; v.u = ((unsigned)h) << 16;
  return v.f;
}

__device__ __forceinline__ unsigned lds_addr(const void* p) {
  return (unsigned)(unsigned long long)(__attribute__((address_space(3))) const void*)p;
}
__device__ __forceinline__ bf16x8 ds128(const void* p) {
  bf16x8 r;
  asm volatile("ds_read_b128 %0, %1" : "=v"(r) : "v"(lds_addr(p)));
  return r;
}
__device__ __forceinline__ i32x4 ds128i(const void* p) {
  i32x4 r;
  asm volatile("ds_read_b128 %0, %1" : "=v"(r) : "v"(lds_addr(p)));
  return r;
}
// 8 fp8(e4m3) -> 8 bf16 (elem order preserved)
__device__ __forceinline__ bf16x8 cvt8(i32x2 v) {
  f32x2 f0 = __builtin_amdgcn_cvt_pk_f32_fp8(v[0], false);
  f32x2 f1 = __builtin_amdgcn_cvt_pk_f32_fp8(v[0], true);
  f32x2 f2 = __builtin_amdgcn_cvt_pk_f32_fp8(v[1], false);
  f32x2 f3 = __builtin_amdgcn_cvt_pk_f32_fp8(v[1], true);
  unsigned w0, w1, w2, w3;
  asm("v_cvt_pk_bf16_f32 %0, %1, %2" : "=v"(w0) : "v"(f0[0]), "v"(f0[1]));
  asm("v_cvt_pk_bf16_f32 %0, %1, %2" : "=v"(w1) : "v"(f1[0]), "v"(f1[1]));
  asm("v_cvt_pk_bf16_f32 %0, %1, %2" : "=v"(w2) : "v"(f2[0]), "v"(f2[1]));
  asm("v_cvt_pk_bf16_f32 %0, %1, %2" : "=v"(w3) : "v"(f3[0]), "v"(f3[1]));
  union { unsigned w[4]; bf16x8 v8; } u;
  u.w[0] = w0; u.w[1] = w1; u.w[2] = w2; u.w[3] = w3;
  return u.v8;
}

// ====== 256x256 8-wave BK=64 core, A-deep(3buf)/B-shallow(2buf) ======
__device__ __forceinline__ void stage_one(const u16* g, int ld, u16* d, int tid) {
  int rw = tid >> 3;
  int gs = ((tid & 7) ^ (rw & 7)) << 3;
  int wb = (tid >> 6) << 9;
#pragma unroll
  for (int p = 0; p < 4; p++)
    GLOAD_LDS(g + (long)(p * 64 + rw) * ld + gs, d + p * 4096 + wb);
}

__device__ __forceinline__ void gemm256d(f32x4 (&acc)[8][4],
    const u16* Ag, int lda, const u16* Bg, int ldb, int nk,
    u16* As, u16* Bs, int tid) {
  const int lane = tid & 63, wid = tid >> 6;
  const int wr = (wid >> 2) << 7;
  const int wc = (wid & 3) << 6;
  const int rl = lane & 15, kg = lane >> 4;
  const int swz0 = (kg ^ (rl & 7)) << 3;
  const int rbA = (wr + rl) * 64, rbB = (wc + rl) * 64;

  stage_one(Ag, lda, As, tid);
  stage_one(Bg, ldb, Bs, tid);
  if (nk > 1) stage_one(Ag + 64, lda, As + 16384, tid);

  int ba = 0;
  for (int t = 0; t < nk; ++t) {
    if (t + 1 < nk) asm volatile("s_waitcnt vmcnt(4)" ::: "memory");
    else            asm volatile("s_waitcnt vmcnt(0)" ::: "memory");
    __builtin_amdgcn_s_barrier();
    if (t + 1 < nk)
      stage_one(Bg + (t + 1) * 64, ldb, Bs + ((t + 1) & 1) * 16384, tid);
    if (t + 2 < nk) {
      int nb = ba + 2; if (nb >= 3) nb -= 3;
      stage_one(Ag + (long)(t + 2) * 64, lda, As + nb * 16384, tid);
    }
    const u16* ab = As + ba * 16384 + rbA;
    const u16* bb = Bs + (t & 1) * 16384 + rbB;
#pragma unroll
    for (int kk = 0; kk < 2; kk++) {
      const int sw = swz0 ^ (kk << 5);
      bf16x8 a[8], b[4];
#pragma unroll
      for (int i = 0; i < 8; i++) a[i] = ds128(ab + i * 1024 + sw);
#pragma unroll
      for (int j = 0; j < 4; j++) b[j] = ds128(bb + j * 1024 + sw);
      asm volatile("s_waitcnt lgkmcnt(0)" ::: "memory");
      __builtin_amdgcn_sched_barrier(0);
      __builtin_amdgcn_s_setprio(1);
#pragma unroll
      for (int i = 0; i < 8; i++)
#pragma unroll
        for (int j = 0; j < 4; j++)
          acc[i][j] = __builtin_amdgcn_mfma_f32_16x16x32_bf16(a[i], b[j], acc[i][j], 0, 0, 0);
      __builtin_amdgcn_s_setprio(0);
      __builtin_amdgcn_sched_barrier(0);
    }
    ba = ba + 1; if (ba == 3) ba = 0;
  }
}

// ====== PV core (r18-proven): 256x128, BK=64, A fp8 kk-interleaved LDS 3buf /
// B bf16 LDS 2buf = 80KB, 2 blocks/CU, never-drain vmcnt(2), 0 bank conflicts.
__device__ __forceinline__ void stage_A64(const u8* gA, u8* Ad, int tid) {
#pragma unroll
  for (int pass = 0; pass < 2; pass++) {
    int gid = pass * 512 + tid;
    int row = gid >> 2, g = gid & 3;
    GLOAD_LDS(gA + (long)row * 2048 + ((g ^ ((row >> 1) & 3)) << 4), Ad + (gid << 4));
  }
}
__device__ __forceinline__ void stage_B64(const u16* gB, u8* Bd, int tid) {
#pragma unroll
  for (int pass = 0; pass < 2; pass++) {
    int gid = pass * 512 + tid;
    int row = gid >> 3, g = gid & 7;
    GLOAD_LDS(gB + (long)row * 2048 + ((g ^ (row & 7)) << 3), Bd + (gid << 4));
  }
}

__device__ __forceinline__ void gemm_pv8(f32x4 (&acc)[4][4],
    const u8* Ag, const u16* Bg, u8* As, u8* Bs, int tid) {
  const int lane = tid & 63, wid = tid >> 6;
  const int mq = wid >> 1, nh = wid & 1;        // 4M x 2N waves, 64x64 each
  const int rl = lane & 15, kg = lane >> 4;
  const int nk = 16;                             // K = 1024 (kc-split half)
  const int abase = (mq * 64 + rl) * 64;
  const int aswz = (kg ^ ((rl >> 1) & 3)) << 4;
  const int bbase = (nh * 64 + rl) * 128;

  stage_A64(Ag, As, tid);                        // A(0)
  stage_B64(Bg, Bs, tid);                        // B(0)
  stage_A64(Ag + 64, As + 16384, tid);           // A(1)
  int ba = 0;
  for (int t = 0; t < nk; ++t) {
    if (t + 1 < nk) asm volatile("s_waitcnt vmcnt(2)" ::: "memory");
    else            asm volatile("s_waitcnt vmcnt(0)" ::: "memory");
    __builtin_amdgcn_s_barrier();
    if (t + 1 < nk) stage_B64(Bg + (t + 1) * 64, Bs + ((t + 1) & 1) * 16384, tid);
    if (t + 2 < nk) {
      int nb = ba + 2; if (nb >= 3) nb -= 3;
      stage_A64(Ag + (long)(t + 2) * 64, As + nb * 16384, tid);
    }
    const u8* ab = As + ba * 16384 + abase;
    const u8* bb = Bs + (t & 1) * 16384 + bbase;
    i32x4 a4[4]; bf16x8 b0[4], b1[4];
#pragma unroll
    for (int i = 0; i < 4; i++) a4[i] = ds128i(ab + i * 1024 + aswz);
#pragma unroll
    for (int j = 0; j < 4; j++) b0[j] = ds128(bb + j * 2048 + ((kg ^ (rl & 7)) << 4));
#pragma unroll
    for (int j = 0; j < 4; j++) b1[j] = ds128(bb + j * 2048 + (((4 + kg) ^ (rl & 7)) << 4));
    asm volatile("s_waitcnt lgkmcnt(4)" ::: "memory");   // A + B-kk0 landed
    __builtin_amdgcn_sched_barrier(0);
    {
      bf16x8 a[4];
#pragma unroll
      for (int i = 0; i < 4; i++) { i32x2 lo; lo[0] = a4[i][0]; lo[1] = a4[i][1]; a[i] = cvt8(lo); }
      __builtin_amdgcn_s_setprio(1);
#pragma unroll
      for (int i = 0; i < 4; i++)
#pragma unroll
        for (int j = 0; j < 4; j++)
          acc[i][j] = __builtin_amdgcn_mfma_f32_16x16x32_bf16(a[i], b0[j], acc[i][j], 0, 0, 0);
      __builtin_amdgcn_s_setprio(0);
    }
    asm volatile("s_waitcnt lgkmcnt(0)" ::: "memory");   // B-kk1 landed
    __builtin_amdgcn_sched_barrier(0);
    {
      bf16x8 a[4];
#pragma unroll
      for (int i = 0; i < 4; i++) { i32x2 hi; hi[0] = a4[i][2]; hi[1] = a4[i][3]; a[i] = cvt8(hi); }
      __builtin_amdgcn_s_setprio(1);
#pragma unroll
      for (int i = 0; i < 4; i++)
#pragma unroll
        for (int j = 0; j < 4; j++)
          acc[i][j] = __builtin_amdgcn_mfma_f32_16x16x32_bf16(a[i], b1[j], acc[i][j], 0, 0, 0);
      __builtin_amdgcn_s_setprio(0);
      __builtin_amdgcn_sched_barrier(0);
    }
    ba = ba + 1; if (ba == 3) ba = 0;
  }
}

struct P6 { const float* p[6]; };
struct O6 { u16* p[6]; };

// ---------------- merged conversion: X, Y, and 6 weight matrices ----------------
// blocks 0..4095 -> X, 4096..8191 -> Y, 8192..8959 -> weights (128 blocks/z)
__global__ __launch_bounds__(256) void k_cvt3(const float* __restrict__ Xf,
                                              const float* __restrict__ Yf, P6 w,
                                              u16* __restrict__ oX, u16* __restrict__ oY,
                                              u16* __restrict__ oW) {
  int bid = blockIdx.x, tid = threadIdx.x;
  const float* in; u16* out; long k;
  if (bid < 8192) {
    int half = bid >> 12;
    in = half ? Yf : Xf; out = half ? oY : oX;
    k = (long)(bid & 4095) * 256 + tid;
  } else {
    int r = bid - 8192;
    int z = r >> 7;
    in = w.p[z]; out = oW + (long)z * 262144;
    k = (long)(r & 127) * 256 + tid;
  }
  const float4* pf = (const float4*)in + k * 2;
  float4 a = pf[0], b = pf[1];
  u16x8 o;
  o[0] = f2bf(a.x); o[1] = f2bf(a.y); o[2] = f2bf(a.z); o[3] = f2bf(a.w);
  o[4] = f2bf(b.x); o[5] = f2bf(b.y); o[6] = f2bf(b.z); o[7] = f2bf(b.w);
  *((u16x8*)out + k) = o;
}

// ---------------- projections (gemm256d core) ----------------
__global__ __launch_bounds__(512) void k_proj2(const u16* __restrict__ Xb, const u16* __restrict__ Yb,
                                               const u16* __restrict__ Wb, P6 bias, O6 dst) {
  __shared__ u16 As[49152], Bs[32768];
  int x = blockIdx.x;
  int swz = (x & 7) * 96 + (x >> 3);
  int grp = swz >= 384;
  int r = grp ? swz - 384 : swz;
  int bm = r / 6, bn = r - bm * 6;
  int tid = threadIdx.x;
  const u16* Ag = (grp ? Yb : Xb) + (long)bm * 256 * 512;
  const u16* Bg = Wb + (long)grp * 786432 + (long)bn * 256 * 512;
  f32x4 acc[8][4] = {};
  gemm256d(acc, Ag, 512, Bg, 512, 8, As, Bs, tid);
  int z = grp * 3 + (bn >> 1);
  const float* bi = bias.p[z];
  u16* D = dst.p[z];
  int lane = tid & 63, wid = tid >> 6;
  int row0 = bm * 256 + ((wid >> 2) << 7) + ((lane >> 4) << 2);
  int colz = (bn & 1) * 256 + ((wid & 3) << 6) + (lane & 15);
  float bj[4];
#pragma unroll
  for (int j = 0; j < 4; j++) bj[j] = bi[colz + (j << 4)];
#pragma unroll
  for (int i = 0; i < 8; i++)
#pragma unroll
    for (int j = 0; j < 4; j++)
#pragma unroll
      for (int rr = 0; rr < 4; rr++)
        D[(long)(row0 + (i << 4) + rr) * 512 + colz + (j << 4)] = f2bf(acc[i][j][rr] + bj[j]);
}

// ---------------- scores (gemm256d): XCD chunk = one batch b ----------------
__global__ __launch_bounds__(512) void k_s(const u16* __restrict__ Q, const u16* __restrict__ K,
                                           u16* __restrict__ S) {
  __shared__ u16 As[49152], Bs[32768];
  int x = blockIdx.x;
  int swz = (x & 7) * 64 + (x >> 3);         // 512 blocks, chunk=64 = one b
  int bn = swz & 7, bm = (swz >> 3) & 7, b = swz >> 6;
  int tid = threadIdx.x;
  const u16* Ag = Q + (long)b * 1048576 + (long)bm * 256 * 512;
  const u16* Bg = K + (long)b * 1048576 + (long)bn * 256 * 512;
  f32x4 acc[8][4] = {};
  gemm256d(acc, Ag, 512, Bg, 512, 8, As, Bs, tid);
  u16* D = S + (long)b * 4194304;
  const float scale = 0.04419417382415922f;  // 1/sqrt(512)
  int lane = tid & 63, wid = tid >> 6;
  int row0 = bm * 256 + ((wid >> 2) << 7) + ((lane >> 4) << 2);
  int col0 = bn * 256 + ((wid & 3) << 6) + (lane & 15);
#pragma unroll
  for (int i = 0; i < 8; i++)
#pragma unroll
    for (int j = 0; j < 4; j++)
#pragma unroll
      for (int rr = 0; rr < 4; rr++)
        D[(long)(row0 + (i << 4) + rr) * 2048 + col0 + (j << 4)] = f2bf(acc[i][j][rr] * scale);
}

// ---------------- softmax over batch axis -> fp8 e4m3, kk-interleaved ----------------
__global__ __launch_bounds__(256) void k_softmax8(const u16* __restrict__ S,
                                                  u8* __restrict__ A8) {
  int idx = blockIdx.x * 256 + threadIdx.x;   // 2048 blocks; 8 m-positions each
  u16x8 v[8];
#pragma unroll
  for (int b = 0; b < 8; b++) v[b] = *((const u16x8*)(S + (long)b * 4194304) + idx);
  unsigned w0[8], w1[8];
#pragma unroll
  for (int jp = 0; jp < 4; jp++) {
    float va[8], vb[8];
    {
      float e[8], m = -1e30f;
#pragma unroll
      for (int b = 0; b < 8; b++) { e[b] = bf2f(v[b][2 * jp]); m = fmaxf(m, e[b]); }
      float s = 0.f;
#pragma unroll
      for (int b = 0; b < 8; b++) { e[b] = __expf(e[b] - m); s += e[b]; }
      float inv = 1.0f / s;
#pragma unroll
      for (int b = 0; b < 8; b++) va[b] = e[b] * inv;
    }
    {
      float e[8], m = -1e30f;
#pragma unroll
      for (int b = 0; b < 8; b++) { e[b] = bf2f(v[b][2 * jp + 1]); m = fmaxf(m, e[b]); }
      float s = 0.f;
#pragma unroll
      for (int b = 0; b < 8; b++) { e[b] = __expf(e[b] - m); s += e[b]; }
      float inv = 1.0f / s;
#pragma unroll
      for (int b = 0; b < 8; b++) vb[b] = e[b] * inv;
    }
#pragma unroll
    for (int b = 0; b < 8; b++) {
      if (jp == 0)      w0[b] = __builtin_amdgcn_cvt_pk_fp8_f32(va[b], vb[b], 0,     false);
      else if (jp == 1) w0[b] = __builtin_amdgcn_cvt_pk_fp8_f32(va[b], vb[b], w0[b], true);
      else if (jp == 2) w1[b] = __builtin_amdgcn_cvt_pk_fp8_f32(va[b], vb[b], 0,     false);
      else              w1[b] = __builtin_amdgcn_cvt_pk_fp8_f32(va[b], vb[b], w1[b], true);
    }
  }
  // permuted chunk index: c' = (c & ~7) | ((c&3)<<1) | ((c>>2)&1)
  long cp = ((long)idx & ~7L) | (((long)idx & 3) << 1) | (((long)idx >> 2) & 1);
#pragma unroll
  for (int b = 0; b < 8; b++) {
    i32x2 w; w[0] = (int)w0[b]; w[1] = (int)w1[b];
    *(i32x2*)(A8 + (long)b * 4194304 + cp * 8) = w;
  }
}

// ---------------- V transpose (bf16) ----------------
__global__ __launch_bounds__(256) void k_tr(const u16* __restrict__ V1, const u16* __restrict__ V2,
                                            u16* __restrict__ T1, u16* __restrict__ T2) {
  __shared__ u16 tile[64][65];
  int z = blockIdx.z;
  const u16* src = (z < 8 ? V1 : V2) + (long)(z & 7) * 1048576;
  u16*       dst = (z < 8 ? T1 : T2) + (long)(z & 7) * 1048576;
  int n0 = blockIdx.x * 64, d0 = blockIdx.y * 64;
  int t = threadIdx.x;
  int r = t >> 2, cs = (t & 3) * 16;
  const u16x8* sp = (const u16x8*)(src + (long)(n0 + r) * 512 + d0 + cs);
  u16x8 a = sp[0], b = sp[1];
#pragma unroll
  for (int jj = 0; jj < 8; jj++) { tile[r][cs + jj] = a[jj]; tile[r][cs + 8 + jj] = b[jj]; }
  __syncthreads();
  u16x8 o0, o1;
#pragma unroll
  for (int jj = 0; jj < 8; jj++) { o0[jj] = tile[cs + jj][r]; o1[jj] = tile[cs + 8 + jj][r]; }
  u16x8* op = (u16x8*)(dst + (long)(d0 + r) * 2048 + n0 + cs);
  op[0] = o0; op[1] = o1;
}

// ---------------- merged PV: pure partials (no X/Y reads in epilogue) ----------------
// 512 blocks (2/CU), kc-split: kc0 -> out = acc ; kc1 -> P = acc.
__global__ __launch_bounds__(512) void k_pv8m(const u8* __restrict__ A2, const u16* __restrict__ Vt1,
                                              const u8* __restrict__ A1, const u16* __restrict__ Vt2,
                                              float* __restrict__ out, float* __restrict__ P) {
  __shared__ u8 As[49152], Bs[32768];   // 80KB -> 2 blocks/CU
  int x = blockIdx.x;
  int swz = (x & 7) * 64 + (x >> 3);    // XCD chunk = one b (64 blocks)
  int b = swz >> 6;
  int r = swz & 63;
  int bn = r & 3, kc = (r >> 2) & 1, bm = r >> 3;
  int tid = threadIdx.x;
  long aoff = (long)b * 4194304 + (long)bm * 256 * 2048 + kc * 1024;
  long voff = (long)b * 1048576 + (long)bn * 128 * 2048 + kc * 1024;
  f32x4 acc[4][4] = {};
  gemm_pv8(acc, A2 + aoff, Vt1 + voff, As, Bs, tid);   // attention 2 half
  __builtin_amdgcn_s_barrier();                        // LDS reuse between halves
  gemm_pv8(acc, A1 + aoff, Vt2 + voff, As, Bs, tid);   // attention 1 half
  int lane = tid & 63, wid = tid >> 6;
  int mq = wid >> 1, nh = wid & 1;
  int row0 = bm * 256 + mq * 64 + ((lane >> 4) << 2);
  int col0 = bn * 128 + nh * 64 + (lane & 15);
  long base = (long)b * 1048576;
  float* D = kc ? P : out;
#pragma unroll
  for (int i = 0; i < 4; i++)
#pragma unroll
    for (int j = 0; j < 4; j++)
#pragma unroll
      for (int rr = 0; rr < 4; rr++) {
        long idx = base + (long)(row0 + (i << 4) + rr) * 512 + col0 + (j << 4);
        D[idx] = acc[i][j][rr];
      }
}

// ---------------- final: out = out + P + X + Y ----------------
__global__ __launch_bounds__(256) void k_fin(float* __restrict__ out, const float* __restrict__ P,
                                             const float* __restrict__ X, const float* __restrict__ Y) {
  long i = (long)(blockIdx.x * 256 + threadIdx.x) * 4;
  float4 o = *(const float4*)(out + i);
  float4 p = *(const float4*)(P + i);
  float4 x = *(const float4*)(X + i);
  float4 y = *(const float4*)(Y + i);
  o.x += p.x + x.x + y.x; o.y += p.y + x.y + y.y;
  o.z += p.z + x.z + y.z; o.w += p.w + x.w + y.w;
  *(float4*)(out + i) = o;
}

extern "C" void kernel_launch(void* const* d_in, const int* in_sizes, int n_in,
                              void* d_out, int out_size, void* d_ws, size_t ws_size,
                              hipStream_t stream) {
  const float* X = (const float*)d_in[0];
  const float* Y = (const float*)d_in[1];
  P6 wp, bp;
  for (int i = 0; i < 6; i++) { wp.p[i] = (const float*)d_in[2 + 2 * i]; bp.p[i] = (const float*)d_in[3 + 2 * i]; }

  const long NX = 8L * 2048 * 512;
  const long NS = 8L * 2048 * 2048;
  u16* p = (u16*)d_ws;
  u16* Xb = p;  p += NX;                  // bf16 X (reused as Vt1)
  u16* Yb = p;  p += NX;                  // bf16 Y (reused as Vt2)
  u16* Wb = p;  p += 6L * 512 * 512;
  u16* Q1 = p;  p += NX;                  // Q1+K2 adjacent -> A8_1 after softmax
  u16* K2 = p;  p += NX;
  u16* Q2 = p;  p += NX;                  // Q2+K1 adjacent -> A8_2 after softmax
  u16* K1 = p;  p += NX;
  u16* Sb = p;  p += NS;                  // S buffer; dead after softmaxes -> Pbuf
  u16* V1 = Sb;
  u16* V2 = Sb + NX;
  u16* Vt1 = Xb;
  u16* Vt2 = Yb;
  u8* A8_2 = (u8*)Q2;                     // NS bytes over dead Q2+K1
  u8* A8_1 = (u8*)Q1;                     // NS bytes over dead Q1+K2
  float* Pbuf = (float*)Sb;               // NX f32 over dead Sb
  (void)ws_size; (void)in_sizes; (void)n_in; (void)out_size;

  dim3 T(256);
  k_cvt3<<<dim3(8960), T, 0, stream>>>(X, Y, wp, Xb, Yb, Wb);
  O6 dst; dst.p[0] = Q1; dst.p[1] = K1; dst.p[2] = V1; dst.p[3] = Q2; dst.p[4] = K2; dst.p[5] = V2;
  k_proj2<<<dim3(768), dim3(512), 0, stream>>>(Xb, Yb, Wb, bp, dst);
  k_tr<<<dim3(32, 8, 16), T, 0, stream>>>(V1, V2, Vt1, Vt2);
  // both score+softmax phases first (frees Sb before PV)
  k_s<<<dim3(512), dim3(512), 0, stream>>>(Q2, K1, Sb);
  k_softmax8<<<dim3(2048), T, 0, stream>>>(Sb, A8_2);
  k_s<<<dim3(512), dim3(512), 0, stream>>>(Q1, K2, Sb);
  k_softmax8<<<dim3(2048), T, 0, stream>>>(Sb, A8_1);
  // merged PV: out(kc0) = A2.V1 + A1.V2 partial ; P(kc1) = partial
  k_pv8m<<<dim3(512), dim3(512), 0, stream>>>(A8_2, Vt1, A8_1, Vt2, (float*)d_out, Pbuf);
  // out = out + P + X + Y
  k_fin<<<dim3((int)(NX / 1024)), T, 0, stream>>>((float*)d_out, Pbuf, X, Y);
}